// Round 5
// baseline (755.059 us; speedup 1.0000x reference)
//
#include <hip/hip_runtime.h>

typedef __bf16 bf16x8 __attribute__((ext_vector_type(8)));
typedef __bf16 bf16x4 __attribute__((ext_vector_type(4)));
typedef float f32x4 __attribute__((ext_vector_type(4)));

#define SCALE 0.17677669529663687f  // 1/sqrt(32)

// ================= shared GEMM body: C[M,256] = A[M,256] @ Wt + bias =========
// MODE 0: C bf16 natural [M][256]
// MODE 1: C bf16 transposed-per-batch vT[(b*256+n)*1024 + tloc]  (M = 4096)
template<int MODE>
__device__ __forceinline__ void gemm_body(const __bf16* __restrict__ A,
    const __bf16* __restrict__ Wt, const float* __restrict__ bias,
    void* __restrict__ Cout, int bx, int by, int tid) {
  const int w = tid >> 6, l = tid & 63;
  const int col = l & 15, quad = l >> 4;
  const int row0 = bx * 64 + w * 16;
  const int col0 = by * 64;
  f32x4 acc[4] = {{0.f,0.f,0.f,0.f},{0.f,0.f,0.f,0.f},{0.f,0.f,0.f,0.f},{0.f,0.f,0.f,0.f}};
  const __bf16* ap = A + (size_t)(row0 + col) * 256 + quad * 8;
  #pragma unroll
  for (int ks = 0; ks < 8; ++ks) {
    bf16x8 af = *(const bf16x8*)(ap + ks * 32);
    #pragma unroll
    for (int n = 0; n < 4; ++n) {
      bf16x8 bf = *(const bf16x8*)(Wt + (size_t)(col0 + n * 16 + col) * 256 + ks * 32 + quad * 8);
      acc[n] = __builtin_amdgcn_mfma_f32_16x16x32_bf16(af, bf, acc[n], 0, 0, 0);
    }
  }
  const int rbase = row0 + quad * 4;
  #pragma unroll
  for (int n = 0; n < 4; ++n) {
    const int cc = col0 + n * 16 + col;
    const float bv = bias ? bias[cc] : 0.0f;
    if (MODE == 0) {
      __bf16* C = (__bf16*)Cout;
      #pragma unroll
      for (int r = 0; r < 4; ++r)
        C[(size_t)(rbase + r) * 256 + cc] = (__bf16)(acc[n][r] + bv);
    } else {
      __bf16* C = (__bf16*)Cout;
      const int bb2 = rbase >> 10, tl = rbase & 1023;
      bf16x4 o4;
      #pragma unroll
      for (int r = 0; r < 4; ++r) o4[r] = (__bf16)(acc[n][r] + bv);
      *(bf16x4*)(C + ((size_t)(bb2 * 256 + cc)) * 1024 + tl) = o4;
    }
  }
}

// ================= L1 "prep": castw (5 weights) + fused LN1+pool =============
// blocks [0,1280): weight cast+transpose.
// blocks [1280,5376): each block owns a 2x2 spatial quad of tokens (wave w ->
// token (qi*2 + (w>>1), qj*2 + (w&1))); LN1 per token + 2x2 mean pool of RAW x
// via a 4 KiB LDS exchange — x is read ONCE (old pool kernel re-read 64 MiB).
__global__ __launch_bounds__(256) void prep_kernel(
    const float* __restrict__ W0, const float* __restrict__ W1,
    const float* __restrict__ W2, const float* __restrict__ W3,
    const float* __restrict__ W4,
    __bf16* __restrict__ T0, __bf16* __restrict__ T1,
    __bf16* __restrict__ T2, __bf16* __restrict__ T3,
    __bf16* __restrict__ T4,
    const float* __restrict__ x, const float* __restrict__ g1,
    const float* __restrict__ b1, __bf16* __restrict__ xn,
    __bf16* __restrict__ xp) {
  __shared__ float4 plds[4][64];
  const int blk = blockIdx.x, tid = threadIdx.x;
  if (blk < 1280) {
    int which = blk >> 8;
    const float* W = which == 0 ? W0 : which == 1 ? W1 : which == 2 ? W2 : which == 3 ? W3 : W4;
    __bf16* T = which == 0 ? T0 : which == 1 ? T1 : which == 2 ? T2 : which == 3 ? T3 : T4;
    int id = (blk & 255) * 256 + tid;
    int kk = id >> 8, n = id & 255;
    T[n * 256 + kk] = (__bf16)W[id];
    return;
  }
  const int w = tid >> 6, lane = tid & 63;
  const int blk2 = blk - 1280;                 // [0,4096)
  const int b = blk2 >> 10, rem = blk2 & 1023;
  const int qi = rem >> 5, qj = rem & 31;
  const int i = qi * 2 + (w >> 1), j = qj * 2 + (w & 1);
  const size_t tok = (size_t)b * 4096 + i * 64 + j;
  const float4 v = *(const float4*)(x + tok * 256 + lane * 4);
  plds[w][lane] = v;                           // raw x for pooling
  // LayerNorm on this token
  float s = v.x + v.y + v.z + v.w;
  #pragma unroll
  for (int off = 32; off; off >>= 1) s += __shfl_down(s, off);
  float mean = __shfl(s, 0) * (1.0f / 256.0f);
  float dx = v.x - mean, dy = v.y - mean, dz = v.z - mean, dw = v.w - mean;
  float vs = dx * dx + dy * dy + dz * dz + dw * dw;
  #pragma unroll
  for (int off = 32; off; off >>= 1) vs += __shfl_down(vs, off);
  float rstd = rsqrtf(__shfl(vs, 0) * (1.0f / 256.0f) + 1e-5f);
  const float4 gg = *(const float4*)(g1 + lane * 4);
  const float4 bv = *(const float4*)(b1 + lane * 4);
  bf16x4 o4;
  o4[0] = (__bf16)(dx * rstd * gg.x + bv.x);
  o4[1] = (__bf16)(dy * rstd * gg.y + bv.y);
  o4[2] = (__bf16)(dz * rstd * gg.z + bv.z);
  o4[3] = (__bf16)(dw * rstd * gg.w + bv.w);
  *(bf16x4*)(xn + tok * 256 + lane * 4) = o4;
  __syncthreads();
  if (w == 0) {
    float4 a0 = plds[0][lane], a1 = plds[1][lane], a2 = plds[2][lane], a3 = plds[3][lane];
    bf16x4 p4;
    p4[0] = (__bf16)(0.25f * (a0.x + a1.x + a2.x + a3.x));
    p4[1] = (__bf16)(0.25f * (a0.y + a1.y + a2.y + a3.y));
    p4[2] = (__bf16)(0.25f * (a0.z + a1.z + a2.z + a3.z));
    p4[3] = (__bf16)(0.25f * (a0.w + a1.w + a2.w + a3.w));
    *(bf16x4*)(xp + ((size_t)(b * 1024 + qi * 32 + qj)) * 256 + lane * 4) = p4;
  }
}

// ================= L2 "qm": Q-GEMM + (mean-GEMM fused with LN2) ==============
__global__ __launch_bounds__(256) void qm_kernel(
    const __bf16* __restrict__ xn, const __bf16* __restrict__ WtQ,
    const float* __restrict__ bq, __bf16* __restrict__ qb,
    const __bf16* __restrict__ xp, const __bf16* __restrict__ WtM,
    const float* __restrict__ g2, const float* __restrict__ b2,
    __bf16* __restrict__ xr) {
  const int blk = blockIdx.x, tid = threadIdx.x;
  if (blk < 1024) {
    gemm_body<0>(xn, WtQ, bq, qb, blk & 255, blk >> 8, tid);
    return;
  }
  const int w = tid >> 6, l = tid & 63;
  const int col = l & 15, quad = l >> 4;
  const int row0 = (blk - 1024) * 64 + w * 16;
  f32x4 acc[16];
  #pragma unroll
  for (int n = 0; n < 16; ++n) acc[n] = (f32x4){0.f, 0.f, 0.f, 0.f};
  const __bf16* ap = xp + (size_t)(row0 + col) * 256 + quad * 8;
  #pragma unroll
  for (int ks = 0; ks < 8; ++ks) {
    bf16x8 af = *(const bf16x8*)(ap + ks * 32);
    #pragma unroll
    for (int n = 0; n < 16; ++n) {
      bf16x8 bf = *(const bf16x8*)(WtM + (size_t)(n * 16 + col) * 256 + ks * 32 + quad * 8);
      acc[n] = __builtin_amdgcn_mfma_f32_16x16x32_bf16(af, bf, acc[n], 0, 0, 0);
    }
  }
  #pragma unroll
  for (int r = 0; r < 4; ++r) {
    float s = 0.f;
    #pragma unroll
    for (int n = 0; n < 16; ++n) s += acc[n][r];
    #pragma unroll
    for (int m = 1; m < 16; m <<= 1) s += __shfl_xor(s, m);
    float mean = s * (1.0f / 256.0f);
    float vs = 0.f;
    #pragma unroll
    for (int n = 0; n < 16; ++n) { float d = acc[n][r] - mean; vs += d * d; }
    #pragma unroll
    for (int m = 1; m < 16; m <<= 1) vs += __shfl_xor(vs, m);
    float rstd = rsqrtf(vs * (1.0f / 256.0f) + 1e-5f);
    int row = row0 + quad * 4 + r;
    #pragma unroll
    for (int n = 0; n < 16; ++n) {
      int cc = n * 16 + col;
      xr[(size_t)row * 256 + cc] = (__bf16)((acc[n][r] - mean) * rstd * g2[cc] + b2[cc]);
    }
  }
}

// ================= L3 "kv": K-GEMM (mode0) + V-GEMM (mode1) ==================
__global__ __launch_bounds__(256) void kv_kernel(
    const __bf16* __restrict__ xr, const __bf16* __restrict__ WtK,
    const float* __restrict__ bk, __bf16* __restrict__ kbuf,
    const __bf16* __restrict__ WtV, const float* __restrict__ bv,
    __bf16* __restrict__ vTb) {
  const int blk = blockIdx.x, tid = threadIdx.x;
  if (blk < 256) gemm_body<0>(xr, WtK, bk, kbuf, blk & 63, blk >> 6, tid);
  else { int k = blk - 256; gemm_body<1>(xr, WtV, bv, vTb, k & 63, k >> 6, tid); }
}

// ================= L5 "o": O-GEMM + bias + resid, fp32 out ===================
__global__ __launch_bounds__(256) void o_kernel(
    const __bf16* __restrict__ oat, const __bf16* __restrict__ WtO,
    const float* __restrict__ bo, const float* __restrict__ resid,
    float* __restrict__ out) {
  __shared__ float sm[4][16][68];
  const int tid = threadIdx.x;
  const int w = tid >> 6, l = tid & 63;
  const int col = l & 15, quad = l >> 4;
  const int row0 = blockIdx.x * 64 + w * 16;
  const int col0 = blockIdx.y * 64;
  f32x4 acc[4] = {{0.f,0.f,0.f,0.f},{0.f,0.f,0.f,0.f},{0.f,0.f,0.f,0.f},{0.f,0.f,0.f,0.f}};
  const __bf16* ap = oat + (size_t)(row0 + col) * 256 + quad * 8;
  #pragma unroll
  for (int ks = 0; ks < 8; ++ks) {
    bf16x8 af = *(const bf16x8*)(ap + ks * 32);
    #pragma unroll
    for (int n = 0; n < 4; ++n) {
      bf16x8 bf = *(const bf16x8*)(WtO + (size_t)(col0 + n * 16 + col) * 256 + ks * 32 + quad * 8);
      acc[n] = __builtin_amdgcn_mfma_f32_16x16x32_bf16(af, bf, acc[n], 0, 0, 0);
    }
  }
  #pragma unroll
  for (int n = 0; n < 4; ++n) {
    const float bv = bo[col0 + n * 16 + col];
    #pragma unroll
    for (int r = 0; r < 4; ++r)
      sm[w][quad * 4 + r][n * 16 + col] = acc[n][r] + bv;
  }
  #pragma unroll
  for (int i = 0; i < 4; ++i) {
    int lr = i * 4 + quad;
    int f4 = l & 15;
    size_t off = (size_t)(row0 + lr) * 256 + col0 + f4 * 4;
    float4 rv = *(const float4*)(resid + off);
    const float* sp = &sm[w][lr][f4 * 4];
    float4 ov;
    ov.x = sp[0] + rv.x; ov.y = sp[1] + rv.y;
    ov.z = sp[2] + rv.z; ov.w = sp[3] + rv.w;
    *(float4*)(out + off) = ov;
  }
}

// ================= L4 fused attention v5: register softmax ===================
// Swapped QK^T (mfma(K,Q)) -> each lane holds S^T for ONE q-row (q = q0+col),
// k = w*256 + t*16 + quad*4 + r: 64 scores fully in registers. Softmax:
// in-lane max/sum + shfl_xor(16,32) + single-barrier cross-wave stats combine
// (merged max/sum: p = exp(x - m_w) * exp(m_w - gm) / gs). No fp32 score LDS
// round-trip at all. Probs: NT-stored to attn straight from regs; written ONCE
// as bf16 (32 KiB, XOR-swizzled) for PV's b128 reads (no cvt in PV loop).
// PV partials aliased into each wave's own dead k-strip of the P tile.
// LDS 72.5 -> 33 KiB; __launch_bounds__(256,3) -> 3 blocks/CU (was 2).
__device__ __forceinline__ void bar_nodrain() {
  __builtin_amdgcn_sched_barrier(0);
  asm volatile("s_waitcnt lgkmcnt(0)" ::: "memory");
  __builtin_amdgcn_s_barrier();
  __builtin_amdgcn_sched_barrier(0);
}

__global__ __launch_bounds__(256, 3) void attn_fused(
    const __bf16* __restrict__ q, const __bf16* __restrict__ kb,
    const __bf16* __restrict__ vT, float* __restrict__ attn,
    __bf16* __restrict__ oat) {
  __shared__ __bf16 Pb[16 * 1024];   // 32 KiB bf16 probs; PV partials aliased
  __shared__ float2 stats[64];       // [w][q] (max, sum)
  float* Pf = (float*)Pb;
  const int tid = threadIdx.x;
  const int w = tid >> 6, l = tid & 63;
  const int col = l & 15, quad = l >> 4;
  const int bh = blockIdx.y, b = bh >> 3, h = bh & 7;
  const int sw = (col & 7) << 3;     // row-swizzle key (row = col for this lane)
  const __bf16* kbase = kb + ((size_t)(b * 1024 + col)) * 256 + h * 32 + quad * 8;
  const __bf16* v0p = vT + ((size_t)(b * 256 + h * 32 + col)) * 1024;
  const __bf16* v1p = v0p + 16 * 1024;

  for (int tile = 0; tile < 2; ++tile) {
    const int q0 = blockIdx.x * 32 + tile * 16;

    // Phase 1: S^T into registers (16 MFMAs, zero C-in each)
    bf16x8 qf = *(const bf16x8*)(q + ((size_t)(b * 4096 + q0 + col)) * 256 + h * 32 + quad * 8);
    f32x4 s[16];
    __builtin_amdgcn_s_setprio(1);
    #pragma unroll
    for (int t = 0; t < 16; ++t) {
      bf16x8 kf = *(const bf16x8*)(kbase + (size_t)(w * 256 + t * 16) * 256);
      s[t] = __builtin_amdgcn_mfma_f32_16x16x32_bf16(kf, qf,
              (f32x4){0.f, 0.f, 0.f, 0.f}, 0, 0, 0);
    }
    __builtin_amdgcn_s_setprio(0);

    // in-lane max over the 64 raw scores of this lane's q-row strip
    f32x4 m4 = s[0];
    #pragma unroll
    for (int t = 1; t < 16; ++t) {
      m4[0] = fmaxf(m4[0], s[t][0]); m4[1] = fmaxf(m4[1], s[t][1]);
      m4[2] = fmaxf(m4[2], s[t][2]); m4[3] = fmaxf(m4[3], s[t][3]);
    }
    float m = fmaxf(fmaxf(m4[0], m4[1]), fmaxf(m4[2], m4[3])) * SCALE;
    m = fmaxf(m, __shfl_xor(m, 16));
    m = fmaxf(m, __shfl_xor(m, 32));   // wave-strip max for this q
    // exp(SCALE*x - m) in-lane; accumulate strip sum
    f32x4 s4 = {0.f, 0.f, 0.f, 0.f};
    #pragma unroll
    for (int t = 0; t < 16; ++t) {
      s[t][0] = __expf(fmaf(s[t][0], SCALE, -m)); s4[0] += s[t][0];
      s[t][1] = __expf(fmaf(s[t][1], SCALE, -m)); s4[1] += s[t][1];
      s[t][2] = __expf(fmaf(s[t][2], SCALE, -m)); s4[2] += s[t][2];
      s[t][3] = __expf(fmaf(s[t][3], SCALE, -m)); s4[3] += s[t][3];
    }
    float sum = (s4[0] + s4[1]) + (s4[2] + s4[3]);
    sum += __shfl_xor(sum, 16);
    sum += __shfl_xor(sum, 32);
    if (l < 16) stats[w * 16 + col] = make_float2(m, sum);
    bar_nodrain();                     // stats visible (cheap: 512 B lgkm)

    // cross-wave combine -> per-q global factor f = exp(m_w - gm) / gs
    float2 e0 = stats[col], e1 = stats[16 + col], e2 = stats[32 + col], e3 = stats[48 + col];
    float gm = fmaxf(fmaxf(e0.x, e1.x), fmaxf(e2.x, e3.x));
    float gs = e0.y * __expf(e0.x - gm) + e1.y * __expf(e1.x - gm)
             + e2.y * __expf(e2.x - gm) + e3.y * __expf(e3.x - gm);
    float f = __expf(m - gm) / gs;

    // NT attn store straight from regs + single bf16 P write (swizzled)
    float* arow = attn + ((size_t)(bh * 4096 + q0 + col)) * 1024 + w * 256 + quad * 4;
    __bf16* prow = Pb + col * 1024;
    const int kb0 = w * 256 + quad * 4;
    #pragma unroll
    for (int t = 0; t < 16; ++t) {
      f32x4 pv;
      pv[0] = s[t][0] * f; pv[1] = s[t][1] * f;
      pv[2] = s[t][2] * f; pv[3] = s[t][3] * f;
      __builtin_nontemporal_store(pv, (f32x4*)(arow + t * 16));
      bf16x4 pbv;
      pbv[0] = (__bf16)pv[0]; pbv[1] = (__bf16)pv[1];
      pbv[2] = (__bf16)pv[2]; pbv[3] = (__bf16)pv[3];
      *(bf16x4*)(prow + (((kb0 + t * 16)) ^ sw)) = pbv;
    }
    bar_nodrain();                     // P visible for PV

    // PV: wave's 256-k strip, bf16 A-frags direct from LDS
    f32x4 a0 = {0.f, 0.f, 0.f, 0.f}, a1 = {0.f, 0.f, 0.f, 0.f};
    __builtin_amdgcn_s_setprio(1);
    #pragma unroll
    for (int s8 = 0; s8 < 8; ++s8) {
      int k0 = w * 256 + s8 * 32 + quad * 8;
      bf16x8 af = *(const bf16x8*)(Pb + col * 1024 + (k0 ^ sw));
      bf16x8 b0 = *(const bf16x8*)(v0p + k0);
      bf16x8 b1 = *(const bf16x8*)(v1p + k0);
      a0 = __builtin_amdgcn_mfma_f32_16x16x32_bf16(af, b0, a0, 0, 0, 0);
      a1 = __builtin_amdgcn_mfma_f32_16x16x32_bf16(af, b1, a1, 0, 0, 0);
    }
    __builtin_amdgcn_s_setprio(0);

    // PV partials into the wave's OWN dead k-strip bytes of Pb (disjoint per
    // wave; own PV reads precede in program order; others' strips untouched)
    #pragma unroll
    for (int r = 0; r < 4; ++r) {
      Pf[(quad * 4 + r) * 512 + w * 128 + col] = a0[r];
      Pf[(quad * 4 + r) * 512 + w * 128 + 16 + col] = a1[r];
    }
    bar_nodrain();                     // partials visible

    #pragma unroll
    for (int it = 0; it < 2; ++it) {
      int idx = tid + it * 256;
      int row = idx >> 5, d = idx & 31;
      float ssum = Pf[row * 512 + d] + Pf[row * 512 + 128 + d]
                 + Pf[row * 512 + 256 + d] + Pf[row * 512 + 384 + d];
      oat[((size_t)(b * 4096 + q0 + row)) * 256 + h * 32 + d] = (__bf16)ssum;
    }
    // tile 2: reduce-reads complete before each wave's next stats-barrier, so
    // the tile-2 P/partial writes (all post-barrier) cannot race them.
  }
}

extern "C" void kernel_launch(void* const* d_in, const int* in_sizes, int n_in,
                              void* d_out, int out_size, void* d_ws, size_t ws_size,
                              hipStream_t stream) {
  (void)in_sizes; (void)n_in; (void)out_size; (void)ws_size;
  const float* x     = (const float*)d_in[0];
  const float* ln1_g = (const float*)d_in[2];
  const float* ln1_b = (const float*)d_in[3];
  const float* Wq    = (const float*)d_in[4];
  const float* bq    = (const float*)d_in[5];
  const float* Wk    = (const float*)d_in[6];
  const float* bk    = (const float*)d_in[7];
  const float* Wv    = (const float*)d_in[8];
  const float* bv    = (const float*)d_in[9];
  const float* Wmean = (const float*)d_in[10];
  const float* ln2_g = (const float*)d_in[11];
  const float* ln2_b = (const float*)d_in[12];
  const float* Wo    = (const float*)d_in[13];
  const float* bo    = (const float*)d_in[14];

  float* out  = (float*)d_out;           // [16384, 256] fp32
  float* attn = out + 4194304;           // [32, 4096, 1024] fp32

  __bf16* w0   = (__bf16*)d_ws;
  __bf16* xn   = w0;                     // 4,194,304
  __bf16* qb   = w0 + 4194304;           // 4,194,304
  __bf16* oat  = w0 + 8388608;           // 4,194,304
  __bf16* xp   = w0 + 12582912;          // 1,048,576
  __bf16* xr   = w0 + 14680064;          // 1,048,576
  __bf16* kbuf = w0 + 15728640;          // 1,048,576
  __bf16* vTb  = w0 + 16777216;          // 1,048,576
  __bf16* WtQ  = w0 + 17825792;          // 5 x 65,536
  __bf16* WtK  = WtQ + 65536;
  __bf16* WtV  = WtK + 65536;
  __bf16* WtM  = WtV + 65536;
  __bf16* WtO  = WtM + 65536;

  // L1: castw(1280) + fused LN1+pool(4096) = 5376 blocks
  prep_kernel<<<5376, 256, 0, stream>>>(Wq, Wk, Wv, Wmean, Wo,
                                        WtQ, WtK, WtV, WtM, WtO,
                                        x, ln1_g, ln1_b, xn, xp);
  // L2: Q-GEMM(1024) + meanGEMM+LN2(64) = 1088 blocks
  qm_kernel<<<1088, 256, 0, stream>>>(xn, WtQ, bq, qb, xp, WtM, ln2_g, ln2_b, xr);
  // L3: K-GEMM(256) + V-GEMM(256) = 512 blocks
  kv_kernel<<<512, 256, 0, stream>>>(xr, WtK, bk, kbuf, WtV, bv, vTb);
  // L4: fused attention v5 (register softmax), 2 q-tiles per block
  attn_fused<<<dim3(128, 32), 256, 0, stream>>>(qb, kbuf, vTb, attn, oat);
  // L5: O-GEMM + bias + residual (LDS-bounce float4 epilogue)
  o_kernel<<<dim3(256, 4), 256, 0, stream>>>(oat, WtO, bo, x, out);
}